// Round 1
// baseline (4991.438 us; speedup 1.0000x reference)
//
#include <hip/hip_runtime.h>
#include <stdint.h>

typedef unsigned long long u64;

#define NB 8
#define NPTS 4096
#define NC 64
#define KOUT 16
#define TSEL 48          // fp32 preselect size (top-48 contains true top-32)
#define CHUNK 64         // 64 rows/chunk: 17.4 KB LDS -> 2x resident blocks
#define PADROW 68        // floats per staged row: 64 + 4 pad breaks bank aliasing
#define NCHUNK (NPTS / CHUNK)

// sq[p]: 8 accumulator chains over stride-8 (numpy pairwise-8 == XLA W8 reduce
// chains), separate mul/add roundings, combined ((r0+r1)+(r2+r3))+((r4+r5)+(r6+r7)).
__global__ __launch_bounds__(256) void sq_kernel(const float* __restrict__ pts,
                                                 float* __restrict__ sqw) {
    int p = blockIdx.x * 256 + threadIdx.x;
    const float* r = pts + (size_t)p * NC;
    float acc[8];
#pragma unroll
    for (int j = 0; j < 8; ++j) acc[j] = __fmul_rn(r[j], r[j]);
#pragma unroll
    for (int i = 8; i < 64; i += 8)
#pragma unroll
        for (int j = 0; j < 8; ++j)
            acc[j] = __fadd_rn(acc[j], __fmul_rn(r[i + j], r[i + j]));
    float s01 = __fadd_rn(acc[0], acc[1]);
    float s23 = __fadd_rn(acc[2], acc[3]);
    float s45 = __fadd_rn(acc[4], acc[5]);
    float s67 = __fadd_rn(acc[6], acc[7]);
    sqw[p] = __fadd_rn(__fadd_rn(s01, s23), __fadd_rn(s45, s67));
}

// Uniform-lane u64 broadcast via v_readlane_b32 (SALU path, no LDS/bpermute).
__device__ __forceinline__ u64 readlane_u64(u64 v, int lane) {
    uint32_t lo = (uint32_t)__builtin_amdgcn_readlane((int)(uint32_t)v, lane);
    uint32_t hi = (uint32_t)__builtin_amdgcn_readlane((int)(uint32_t)(v >> 32), lane);
    return ((u64)hi << 32) | (u64)lo;
}

// Maintain an ascending sorted 64-list, one u64 per lane (dist_bits<<32 | idx).
// Threshold = lane 47 (48th smallest). Wave-parallel shift insert.
// All uniform broadcasts use readlane (SGPR), only the shift uses DS ops.
__device__ __forceinline__ void stream_insert(u64& list, u64 cand, int lane) {
    u64 thr = readlane_u64(list, 47);
    u64 mask = __ballot(cand < thr);
    while (mask) {
        int src = __ffsll((long long)mask) - 1;
        u64 v = readlane_u64(cand, src);          // wave-uniform src lane
        int pos = __popcll(__ballot(list < v));
        u64 up = __shfl_up(list, 1);
        list = (lane < pos) ? list : ((lane == pos) ? v : up);
        mask &= (mask - 1);
    }
}

// Inner product as XLA:CPU dot_general (Eigen gebp) / BLAS sgemm computes it:
// per output element, ONE sequential FMA chain over k = 0..63 ascending.
__device__ __forceinline__ float ref_inner(const float4 (&xq)[16],
                                           const float4 (&yv)[16]) {
    float acc = 0.f;
#pragma unroll
    for (int i = 0; i < 16; ++i) {
        acc = __fmaf_rn(xq[i].x, yv[i].x, acc);
        acc = __fmaf_rn(xq[i].y, yv[i].y, acc);
        acc = __fmaf_rn(xq[i].z, yv[i].z, acc);
        acc = __fmaf_rn(xq[i].w, yv[i].w, acc);
    }
    return acc;
}

// Re-rank the 48 fp32-preselected candidates by the emulated reference key:
// key = fl(fl(sq_n - fl(2*inner)) + sq_m). Ties by index (top_k stable).
__device__ __forceinline__ void epilogue(u64 list, int n, int b, int lane,
                                         const float4 (&xq)[16],
                                         const float* __restrict__ pb,
                                         const float* __restrict__ sqb,
                                         float sqn,
                                         const float* __restrict__ xyz,
                                         float* __restrict__ out) {
    int m = (int)(uint32_t)list;          // every lane holds a real index after chunk 0
    const float4* yr = (const float4*)(pb + (size_t)m * NC);
    float4 yv[16];
#pragma unroll
    for (int i = 0; i < 16; ++i) yv[i] = yr[i];
    float inner = ref_inner(xq, yv);
    float key = __fadd_rn(__fsub_rn(sqn, __fmul_rn(2.0f, inner)), sqb[m]);

    int rank = 0;
    uint32_t kb = __float_as_uint(key);
#pragma unroll 1
    for (int j = 0; j < TSEL; ++j) {
        float kj = __uint_as_float(
            (uint32_t)__builtin_amdgcn_readlane((int)kb, j));
        int mj = __builtin_amdgcn_readlane(m, j);
        bool less = (kj < key) || (kj == key && mj < m);   // stable: lower idx first
        rank += less ? 1 : 0;
    }
    if (lane < TSEL && rank < 2 * KOUT && (rank & 1) == 0) {  // dilation D=2: even ranks
        int k = rank >> 1;
        const float* xn = xyz + ((size_t)b * NPTS + n) * 3;
        const float* xm = xyz + ((size_t)b * NPTS + m) * 3;
        float xnx = xn[0], xny = xn[1], xnz = xn[2];
        float ox = xm[0], oy = xm[1], oz = xm[2];
        float rx = xnx - ox, ry = xny - oy, rz = xnz - oz;
        float dis = sqrtf(rx * rx + ry * ry + rz * rz);
        float* o = out + (((size_t)b * NPTS + n) * KOUT + k) * 10;
        o[0] = dis; o[1] = rx; o[2] = ry; o[3] = rz;
        o[4] = xnx; o[5] = xny; o[6] = xnz;
        o[7] = ox;  o[8] = oy;  o[9] = oz;
    }
}

__global__ __launch_bounds__(256, 4) void knn_kernel(
    const float* __restrict__ xyz,
    const float* __restrict__ pts,
    const float* __restrict__ sqw,
    float* __restrict__ out) {

    __shared__ float ylds[CHUNK * PADROW];   // 17.4 KB

    const int tid = threadIdx.x;
    const int lane = tid & 63;
    const int wave = tid >> 6;
    const int b = blockIdx.x >> 9;                  // 512 blocks per batch
    const int rowbase = (blockIdx.x & 511) << 3;    // 8 rows per block
    const int n0 = rowbase + wave * 2;
    const int n1 = n0 + 1;
    const float* pb = pts + (size_t)b * NPTS * NC;
    const float* sqb = sqw + (size_t)b * NPTS;

    // x-features for the wave's two rows, replicated per lane (128 VGPRs)
    float4 x0q[16], x1q[16];
    {
        const float4* xr0 = (const float4*)(pb + (size_t)n0 * NC);
        const float4* xr1 = (const float4*)(pb + (size_t)n1 * NC);
#pragma unroll
        for (int i = 0; i < 16; ++i) { x0q[i] = xr0[i]; x1q[i] = xr1[i]; }
    }
    const float sqn0 = sqb[n0];
    const float sqn1 = sqb[n1];

    u64 list0 = ~0ull, list1 = ~0ull;

    const float4* gsrc = (const float4*)pb;
    float4 pf[4];
#pragma unroll
    for (int j = 0; j < 4; ++j) pf[j] = gsrc[tid + 256 * j];   // prefetch chunk 0

    for (int c = 0; c < NCHUNK; ++c) {
        __syncthreads();   // previous chunk fully consumed
#pragma unroll
        for (int j = 0; j < 4; ++j) {
            int s = tid + 256 * j;
            int ml = s >> 4;
            int c4 = s & 15;
            *(float4*)&ylds[ml * PADROW + c4 * 4] = pf[j];
        }
        __syncthreads();
        if (c + 1 < NCHUNK) {
#pragma unroll
            for (int j = 0; j < 4; ++j)
                pf[j] = gsrc[(size_t)(c + 1) * (CHUNK * 16) + tid + 256 * j];
        }
        {
            const int m = c * CHUNK + lane;
            const float* yr = &ylds[lane * PADROW];
            float a0x = 0.f, a0y = 0.f, a0z = 0.f, a0w = 0.f;
            float a1x = 0.f, a1y = 0.f, a1z = 0.f, a1w = 0.f;
#pragma unroll
            for (int i = 0; i < 16; ++i) {
                float4 y = *(const float4*)(yr + i * 4);
                a0x = fmaf(x0q[i].x, y.x, a0x);
                a0y = fmaf(x0q[i].y, y.y, a0y);
                a0z = fmaf(x0q[i].z, y.z, a0z);
                a0w = fmaf(x0q[i].w, y.w, a0w);
                a1x = fmaf(x1q[i].x, y.x, a1x);
                a1y = fmaf(x1q[i].y, y.y, a1y);
                a1z = fmaf(x1q[i].z, y.z, a1z);
                a1w = fmaf(x1q[i].w, y.w, a1w);
            }
            float ip0 = (a0x + a0y) + (a0z + a0w);
            float ip1 = (a1x + a1y) + (a1z + a1w);
            float sqm = sqb[m];
            // streaming preselect key; ~1e-4 accurate, final ranking is the
            // epilogue's emulated key (margin to rank 48 is >>1e-4)
            float t0 = fmaxf(fmaf(-2.f, ip0, sqn0 + sqm), 0.f);
            float t1 = fmaxf(fmaf(-2.f, ip1, sqn1 + sqm), 0.f);
            stream_insert(list0, ((u64)__float_as_uint(t0) << 32) | (unsigned)m, lane);
            stream_insert(list1, ((u64)__float_as_uint(t1) << 32) | (unsigned)m, lane);
        }
    }

    epilogue(list0, n0, b, lane, x0q, pb, sqb, sqn0, xyz, out);
    epilogue(list1, n1, b, lane, x1q, pb, sqb, sqn1, xyz, out);
}

extern "C" void kernel_launch(void* const* d_in, const int* in_sizes, int n_in,
                              void* d_out, int out_size, void* d_ws, size_t ws_size,
                              hipStream_t stream) {
    const float* xyz = (const float*)d_in[0];   // [8,4096,3]
    const float* pts = (const float*)d_in[1];   // [8,4096,64]
    float* sqw = (float*)d_ws;                  // 32768 floats = 128 KB scratch
    float* out = (float*)d_out;                 // [8,4096,16,10]

    sq_kernel<<<(NB * NPTS) / 256, 256, 0, stream>>>(pts, sqw);
    knn_kernel<<<(NB * NPTS) / 8, 256, 0, stream>>>(xyz, pts, sqw, out);
}

// Round 2
// 1678.695 us; speedup vs baseline: 2.9734x; 2.9734x over previous
//
#include <hip/hip_runtime.h>
#include <stdint.h>

typedef unsigned long long u64;

#define NB 8
#define NPTS 4096
#define NC 64
#define KOUT 16
#define TSEL 48          // fp32 preselect size (top-48 contains true top-32)
#define CHUNK 64         // 64 rows/chunk: 17.4 KB LDS -> 4 blocks/CU
#define PADROW 68        // floats per staged row: 64 + 4 pad breaks bank aliasing
#define NCHUNK (NPTS / CHUNK)

// sq[p]: 8 accumulator chains over stride-8 (numpy pairwise-8 == XLA W8 reduce
// chains), separate mul/add roundings, combined ((r0+r1)+(r2+r3))+((r4+r5)+(r6+r7)).
__global__ __launch_bounds__(256) void sq_kernel(const float* __restrict__ pts,
                                                 float* __restrict__ sqw) {
    int p = blockIdx.x * 256 + threadIdx.x;
    const float* r = pts + (size_t)p * NC;
    float acc[8];
#pragma unroll
    for (int j = 0; j < 8; ++j) acc[j] = __fmul_rn(r[j], r[j]);
#pragma unroll
    for (int i = 8; i < 64; i += 8)
#pragma unroll
        for (int j = 0; j < 8; ++j)
            acc[j] = __fadd_rn(acc[j], __fmul_rn(r[i + j], r[i + j]));
    float s01 = __fadd_rn(acc[0], acc[1]);
    float s23 = __fadd_rn(acc[2], acc[3]);
    float s45 = __fadd_rn(acc[4], acc[5]);
    float s67 = __fadd_rn(acc[6], acc[7]);
    sqw[p] = __fadd_rn(__fadd_rn(s01, s23), __fadd_rn(s45, s67));
}

// Uniform-lane u64 broadcast via v_readlane_b32 (SALU path, no LDS/bpermute).
__device__ __forceinline__ u64 readlane_u64(u64 v, int lane) {
    uint32_t lo = (uint32_t)__builtin_amdgcn_readlane((int)(uint32_t)v, lane);
    uint32_t hi = (uint32_t)__builtin_amdgcn_readlane((int)(uint32_t)(v >> 32), lane);
    return ((u64)hi << 32) | (u64)lo;
}

// Maintain an ascending sorted 64-list, one u64 per lane (dist_bits<<32 | idx).
// Threshold = lane 47 (48th smallest). Wave-parallel shift insert.
// All uniform broadcasts use readlane (SGPR), only the shift uses DS ops.
__device__ __forceinline__ void stream_insert(u64& list, u64 cand, int lane) {
    u64 thr = readlane_u64(list, 47);
    u64 mask = __ballot(cand < thr);
    while (mask) {
        int src = __ffsll((long long)mask) - 1;
        u64 v = readlane_u64(cand, src);          // wave-uniform src lane
        int pos = __popcll(__ballot(list < v));
        u64 up = __shfl_up(list, 1);
        list = (lane < pos) ? list : ((lane == pos) ? v : up);
        mask &= (mask - 1);
    }
}

// Inner product as XLA:CPU dot_general (Eigen gebp) / BLAS sgemm computes it:
// per output element, ONE sequential FMA chain over k = 0..63 ascending.
__device__ __forceinline__ float ref_inner(const float4 (&xq)[16],
                                           const float4 (&yv)[16]) {
    float acc = 0.f;
#pragma unroll
    for (int i = 0; i < 16; ++i) {
        acc = __fmaf_rn(xq[i].x, yv[i].x, acc);
        acc = __fmaf_rn(xq[i].y, yv[i].y, acc);
        acc = __fmaf_rn(xq[i].z, yv[i].z, acc);
        acc = __fmaf_rn(xq[i].w, yv[i].w, acc);
    }
    return acc;
}

// Re-rank the 48 fp32-preselected candidates by the emulated reference key:
// key = fl(fl(sq_n - fl(2*inner)) + sq_m). Ties by index (top_k stable).
__device__ __forceinline__ void epilogue(u64 list, int n, int b, int lane,
                                         const float4 (&xq)[16],
                                         const float* __restrict__ pb,
                                         const float* __restrict__ sqb,
                                         float sqn,
                                         const float* __restrict__ xyz,
                                         float* __restrict__ out) {
    int m = (int)(uint32_t)list;          // every lane holds a real index after chunk 0
    const float4* yr = (const float4*)(pb + (size_t)m * NC);
    float4 yv[16];
#pragma unroll
    for (int i = 0; i < 16; ++i) yv[i] = yr[i];
    float inner = ref_inner(xq, yv);
    float key = __fadd_rn(__fsub_rn(sqn, __fmul_rn(2.0f, inner)), sqb[m]);

    int rank = 0;
    uint32_t kb = __float_as_uint(key);
#pragma unroll 1
    for (int j = 0; j < TSEL; ++j) {
        float kj = __uint_as_float(
            (uint32_t)__builtin_amdgcn_readlane((int)kb, j));
        int mj = __builtin_amdgcn_readlane(m, j);
        bool less = (kj < key) || (kj == key && mj < m);   // stable: lower idx first
        rank += less ? 1 : 0;
    }
    if (lane < TSEL && rank < 2 * KOUT && (rank & 1) == 0) {  // dilation D=2: even ranks
        int k = rank >> 1;
        const float* xn = xyz + ((size_t)b * NPTS + n) * 3;
        const float* xm = xyz + ((size_t)b * NPTS + m) * 3;
        float xnx = xn[0], xny = xn[1], xnz = xn[2];
        float ox = xm[0], oy = xm[1], oz = xm[2];
        float rx = xnx - ox, ry = xny - oy, rz = xnz - oz;
        float dis = sqrtf(rx * rx + ry * ry + rz * rz);
        float* o = out + (((size_t)b * NPTS + n) * KOUT + k) * 10;
        o[0] = dis; o[1] = rx; o[2] = ry; o[3] = rz;
        o[4] = xnx; o[5] = xny; o[6] = xnz;
        o[7] = ox;  o[8] = oy;  o[9] = oz;
    }
}

__global__ __launch_bounds__(256, 2) void knn_kernel(
    const float* __restrict__ xyz,
    const float* __restrict__ pts,
    const float* __restrict__ sqw,
    float* __restrict__ out) {

    __shared__ float ylds[CHUNK * PADROW];   // 17.4 KB

    const int tid = threadIdx.x;
    const int lane = tid & 63;
    const int wave = tid >> 6;
    const int b = blockIdx.x >> 9;                  // 512 blocks per batch
    const int rowbase = (blockIdx.x & 511) << 3;    // 8 rows per block
    const int n0 = rowbase + wave * 2;
    const int n1 = n0 + 1;
    const float* pb = pts + (size_t)b * NPTS * NC;
    const float* sqb = sqw + (size_t)b * NPTS;

    // x-features for the wave's two rows, replicated per lane (128 VGPRs)
    float4 x0q[16], x1q[16];
    {
        const float4* xr0 = (const float4*)(pb + (size_t)n0 * NC);
        const float4* xr1 = (const float4*)(pb + (size_t)n1 * NC);
#pragma unroll
        for (int i = 0; i < 16; ++i) { x0q[i] = xr0[i]; x1q[i] = xr1[i]; }
    }
    const float sqn0 = sqb[n0];
    const float sqn1 = sqb[n1];

    u64 list0 = ~0ull, list1 = ~0ull;

    const float4* gsrc = (const float4*)pb;
    float4 pf[4];
#pragma unroll
    for (int j = 0; j < 4; ++j) pf[j] = gsrc[tid + 256 * j];   // prefetch chunk 0

    for (int c = 0; c < NCHUNK; ++c) {
        __syncthreads();   // previous chunk fully consumed
#pragma unroll
        for (int j = 0; j < 4; ++j) {
            int s = tid + 256 * j;
            int ml = s >> 4;
            int c4 = s & 15;
            *(float4*)&ylds[ml * PADROW + c4 * 4] = pf[j];
        }
        __syncthreads();
        if (c + 1 < NCHUNK) {
#pragma unroll
            for (int j = 0; j < 4; ++j)
                pf[j] = gsrc[(size_t)(c + 1) * (CHUNK * 16) + tid + 256 * j];
        }
        {
            const int m = c * CHUNK + lane;
            const float* yr = &ylds[lane * PADROW];
            float a0x = 0.f, a0y = 0.f, a0z = 0.f, a0w = 0.f;
            float a1x = 0.f, a1y = 0.f, a1z = 0.f, a1w = 0.f;
#pragma unroll
            for (int i = 0; i < 16; ++i) {
                float4 y = *(const float4*)(yr + i * 4);
                a0x = fmaf(x0q[i].x, y.x, a0x);
                a0y = fmaf(x0q[i].y, y.y, a0y);
                a0z = fmaf(x0q[i].z, y.z, a0z);
                a0w = fmaf(x0q[i].w, y.w, a0w);
                a1x = fmaf(x1q[i].x, y.x, a1x);
                a1y = fmaf(x1q[i].y, y.y, a1y);
                a1z = fmaf(x1q[i].z, y.z, a1z);
                a1w = fmaf(x1q[i].w, y.w, a1w);
            }
            float ip0 = (a0x + a0y) + (a0z + a0w);
            float ip1 = (a1x + a1y) + (a1z + a1w);
            float sqm = sqb[m];
            // streaming preselect key; ~1e-4 accurate, final ranking is the
            // epilogue's emulated key (margin to rank 48 is >>1e-4)
            float t0 = fmaxf(fmaf(-2.f, ip0, sqn0 + sqm), 0.f);
            float t1 = fmaxf(fmaf(-2.f, ip1, sqn1 + sqm), 0.f);
            stream_insert(list0, ((u64)__float_as_uint(t0) << 32) | (unsigned)m, lane);
            stream_insert(list1, ((u64)__float_as_uint(t1) << 32) | (unsigned)m, lane);
        }
    }

    epilogue(list0, n0, b, lane, x0q, pb, sqb, sqn0, xyz, out);
    epilogue(list1, n1, b, lane, x1q, pb, sqb, sqn1, xyz, out);
}

extern "C" void kernel_launch(void* const* d_in, const int* in_sizes, int n_in,
                              void* d_out, int out_size, void* d_ws, size_t ws_size,
                              hipStream_t stream) {
    const float* xyz = (const float*)d_in[0];   // [8,4096,3]
    const float* pts = (const float*)d_in[1];   // [8,4096,64]
    float* sqw = (float*)d_ws;                  // 32768 floats = 128 KB scratch
    float* out = (float*)d_out;                 // [8,4096,16,10]

    sq_kernel<<<(NB * NPTS) / 256, 256, 0, stream>>>(pts, sqw);
    knn_kernel<<<(NB * NPTS) / 8, 256, 0, stream>>>(xyz, pts, sqw, out);
}

// Round 5
// 1566.388 us; speedup vs baseline: 3.1866x; 1.0717x over previous
//
#include <hip/hip_runtime.h>
#include <stdint.h>

typedef unsigned long long u64;

#define NB 8
#define NPTS 4096
#define NC 64
#define KOUT 16
#define TSEL 48          // fp32 preselect size (top-48 contains true top-32)
#define CHUNK 64         // candidate rows per staged chunk
#define PADROW 68        // floats per staged row: 64 + 4 pad breaks bank aliasing
#define NCHUNK (NPTS / CHUNK)

// sq[p]: 8 accumulator chains over stride-8 (numpy pairwise-8 == XLA W8 reduce
// chains), separate mul/add roundings, combined ((r0+r1)+(r2+r3))+((r4+r5)+(r6+r7)).
__global__ __launch_bounds__(256) void sq_kernel(const float* __restrict__ pts,
                                                 float* __restrict__ sqw) {
    int p = blockIdx.x * 256 + threadIdx.x;
    const float* r = pts + (size_t)p * NC;
    float acc[8];
#pragma unroll
    for (int j = 0; j < 8; ++j) acc[j] = __fmul_rn(r[j], r[j]);
#pragma unroll
    for (int i = 8; i < 64; i += 8)
#pragma unroll
        for (int j = 0; j < 8; ++j)
            acc[j] = __fadd_rn(acc[j], __fmul_rn(r[i + j], r[i + j]));
    float s01 = __fadd_rn(acc[0], acc[1]);
    float s23 = __fadd_rn(acc[2], acc[3]);
    float s45 = __fadd_rn(acc[4], acc[5]);
    float s67 = __fadd_rn(acc[6], acc[7]);
    sqw[p] = __fadd_rn(__fadd_rn(s01, s23), __fadd_rn(s45, s67));
}

// Uniform-lane u64 broadcast via v_readlane_b32 (SALU path, no LDS/bpermute).
__device__ __forceinline__ u64 readlane_u64(u64 v, int lane) {
    uint32_t lo = (uint32_t)__builtin_amdgcn_readlane((int)(uint32_t)v, lane);
    uint32_t hi = (uint32_t)__builtin_amdgcn_readlane((int)(uint32_t)(v >> 32), lane);
    return ((u64)hi << 32) | (u64)lo;
}

// Maintain an ascending sorted 64-list, one u64 per lane (dist_bits<<32 | idx).
// Threshold = lane 47 (48th smallest). Wave-parallel shift insert.
// All uniform broadcasts use readlane (SGPR), only the shift uses DS ops.
__device__ __forceinline__ void stream_insert(u64& list, u64 cand, int lane) {
    u64 thr = readlane_u64(list, 47);
    u64 mask = __ballot(cand < thr);
    while (mask) {
        int src = __ffsll((long long)mask) - 1;
        u64 v = readlane_u64(cand, src);          // wave-uniform src lane
        int pos = __popcll(__ballot(list < v));
        u64 up = __shfl_up(list, 1);
        list = (lane < pos) ? list : ((lane == pos) ? v : up);
        mask &= (mask - 1);
    }
}

// Inner product as XLA:CPU dot_general (Eigen gebp) / BLAS sgemm computes it:
// per output element, ONE sequential FMA chain over k = 0..63 ascending.
__device__ __forceinline__ float ref_inner(const float4 (&xq)[16],
                                           const float4 (&yv)[16]) {
    float acc = 0.f;
#pragma unroll
    for (int i = 0; i < 16; ++i) {
        acc = __fmaf_rn(xq[i].x, yv[i].x, acc);
        acc = __fmaf_rn(xq[i].y, yv[i].y, acc);
        acc = __fmaf_rn(xq[i].z, yv[i].z, acc);
        acc = __fmaf_rn(xq[i].w, yv[i].w, acc);
    }
    return acc;
}

// Re-rank the 48 fp32-preselected candidates by the emulated reference key:
// key = fl(fl(sq_n - fl(2*inner)) + sq_m). Ties by index (top_k stable).
__device__ __forceinline__ void epilogue(u64 list, int n, int b, int lane,
                                         const float4 (&xq)[16],
                                         const float* __restrict__ pb,
                                         const float* __restrict__ sqb,
                                         float sqn,
                                         const float* __restrict__ xyz,
                                         float* __restrict__ out) {
    int m = (int)(uint32_t)list;          // every lane holds a real index after chunk 0
    const float4* yr = (const float4*)(pb + (size_t)m * NC);
    float4 yv[16];
#pragma unroll
    for (int i = 0; i < 16; ++i) yv[i] = yr[i];
    float inner = ref_inner(xq, yv);
    float key = __fadd_rn(__fsub_rn(sqn, __fmul_rn(2.0f, inner)), sqb[m]);

    int rank = 0;
    uint32_t kb = __float_as_uint(key);
#pragma unroll 1
    for (int j = 0; j < TSEL; ++j) {
        float kj = __uint_as_float(
            (uint32_t)__builtin_amdgcn_readlane((int)kb, j));
        int mj = __builtin_amdgcn_readlane(m, j);
        bool less = (kj < key) || (kj == key && mj < m);   // stable: lower idx first
        rank += less ? 1 : 0;
    }
    if (lane < TSEL && rank < 2 * KOUT && (rank & 1) == 0) {  // dilation D=2: even ranks
        int k = rank >> 1;
        const float* xn = xyz + ((size_t)b * NPTS + n) * 3;
        const float* xm = xyz + ((size_t)b * NPTS + m) * 3;
        float xnx = xn[0], xny = xn[1], xnz = xn[2];
        float ox = xm[0], oy = xm[1], oz = xm[2];
        float rx = xnx - ox, ry = xny - oy, rz = xnz - oz;
        float dis = sqrtf(rx * rx + ry * ry + rz * rz);
        float* o = out + (((size_t)b * NPTS + n) * KOUT + k) * 10;
        o[0] = dis; o[1] = rx; o[2] = ry; o[3] = rz;
        o[4] = xnx; o[5] = xny; o[6] = xnz;
        o[7] = ox;  o[8] = oy;  o[9] = oz;
    }
}

__global__ __launch_bounds__(256, 2) void knn_kernel(
    const float* __restrict__ xyz,
    const float* __restrict__ pts,
    const float* __restrict__ sqw,
    float* __restrict__ out) {

    // double-buffered fp32 tile: 2 * 64 rows * 68 floats * 4B = 34.8 KB
    __shared__ __align__(16) float ylds[2][CHUNK * PADROW];

    const int tid = threadIdx.x;
    const int lane = tid & 63;
    const int wave = tid >> 6;
    const int b = blockIdx.x >> 9;                  // 512 blocks per batch
    const int rowbase = (blockIdx.x & 511) << 3;    // 8 rows per block
    const int n0 = rowbase + wave * 2;
    const int n1 = n0 + 1;
    const float* pb = pts + (size_t)b * NPTS * NC;
    const float* sqb = sqw + (size_t)b * NPTS;

    // x-features for the wave's two rows, replicated per lane (128 VGPRs)
    float4 x0q[16], x1q[16];
    {
        const float4* xr0 = (const float4*)(pb + (size_t)n0 * NC);
        const float4* xr1 = (const float4*)(pb + (size_t)n1 * NC);
#pragma unroll
        for (int i = 0; i < 16; ++i) { x0q[i] = xr0[i]; x1q[i] = xr1[i]; }
    }
    const float sqn0 = sqb[n0];
    const float sqn1 = sqb[n1];

    u64 list0 = ~0ull, list1 = ~0ull;

    const float4* gsrc = (const float4*)pb;
    float4 pf[4];
#pragma unroll
    for (int j = 0; j < 4; ++j) pf[j] = gsrc[tid + 256 * j];   // prefetch chunk 0

    // stage chunk 0 into buffer 0
#pragma unroll
    for (int j = 0; j < 4; ++j) {
        int s = tid + 256 * j;
        int ml = s >> 4;
        int c4 = s & 15;
        *(float4*)&ylds[0][ml * PADROW + c4 * 4] = pf[j];
    }
    __syncthreads();

    for (int c = 0; c < NCHUNK; ++c) {
        const int cb = c & 1;
        if (c + 1 < NCHUNK) {
#pragma unroll
            for (int j = 0; j < 4; ++j)
                pf[j] = gsrc[(size_t)(c + 1) * (CHUNK * 16) + tid + 256 * j];
        }
        {
            const int m = c * CHUNK + lane;
            const float* yr = &ylds[cb][lane * PADROW];
            float a0x = 0.f, a0y = 0.f, a0z = 0.f, a0w = 0.f;
            float a1x = 0.f, a1y = 0.f, a1z = 0.f, a1w = 0.f;
#pragma unroll
            for (int i = 0; i < 16; ++i) {
                float4 y = *(const float4*)(yr + i * 4);
                a0x = fmaf(x0q[i].x, y.x, a0x);
                a0y = fmaf(x0q[i].y, y.y, a0y);
                a0z = fmaf(x0q[i].z, y.z, a0z);
                a0w = fmaf(x0q[i].w, y.w, a0w);
                a1x = fmaf(x1q[i].x, y.x, a1x);
                a1y = fmaf(x1q[i].y, y.y, a1y);
                a1z = fmaf(x1q[i].z, y.z, a1z);
                a1w = fmaf(x1q[i].w, y.w, a1w);
            }
            float ip0 = (a0x + a0y) + (a0z + a0w);
            float ip1 = (a1x + a1y) + (a1z + a1w);
            float sqm = sqb[m];
            // streaming preselect key; ~1e-4 accurate, final ranking is the
            // epilogue's emulated key (margin to rank 48 is >>1e-4)
            float t0 = fmaxf(fmaf(-2.f, ip0, sqn0 + sqm), 0.f);
            float t1 = fmaxf(fmaf(-2.f, ip1, sqn1 + sqm), 0.f);
            stream_insert(list0, ((u64)__float_as_uint(t0) << 32) | (unsigned)m, lane);
            stream_insert(list1, ((u64)__float_as_uint(t1) << 32) | (unsigned)m, lane);
        }
        if (c + 1 < NCHUNK) {
            const int nbuf = cb ^ 1;
#pragma unroll
            for (int j = 0; j < 4; ++j) {
                int s = tid + 256 * j;
                int ml = s >> 4;
                int c4 = s & 15;
                *(float4*)&ylds[nbuf][ml * PADROW + c4 * 4] = pf[j];
            }
        }
        __syncthreads();   // one barrier per chunk: next buffer fully staged
    }

    epilogue(list0, n0, b, lane, x0q, pb, sqb, sqn0, xyz, out);
    epilogue(list1, n1, b, lane, x1q, pb, sqb, sqn1, xyz, out);
}

extern "C" void kernel_launch(void* const* d_in, const int* in_sizes, int n_in,
                              void* d_out, int out_size, void* d_ws, size_t ws_size,
                              hipStream_t stream) {
    const float* xyz = (const float*)d_in[0];   // [8,4096,3]
    const float* pts = (const float*)d_in[1];   // [8,4096,64]
    float* sqw = (float*)d_ws;                  // 32768 floats = 128 KB scratch
    float* out = (float*)d_out;                 // [8,4096,16,10]

    sq_kernel<<<(NB * NPTS) / 256, 256, 0, stream>>>(pts, sqw);
    knn_kernel<<<(NB * NPTS) / 8, 256, 0, stream>>>(xyz, pts, sqw, out);
}

// Round 6
// 1488.295 us; speedup vs baseline: 3.3538x; 1.0525x over previous
//
#include <hip/hip_runtime.h>
#include <stdint.h>

typedef unsigned long long u64;

#define NB 8
#define NPTS 4096
#define NC 64
#define KOUT 16
#define TSEL 48          // preselect size (top-48 contains true top-32; gap analysis 100x margin)
#define CHUNK 64         // candidate rows per staged chunk
#define PADROW 68        // floats per staged row: 64 + 4 pad breaks bank aliasing
#define NCHUNK (NPTS / CHUNK)
#define IDXBITS 0xFFFu   // low 12 bits hold candidate index (NPTS = 4096)
#define KEYMASK 0xFFFFF000u

// sq[p]: 8 accumulator chains over stride-8 (numpy pairwise-8 == XLA W8 reduce
// chains), separate mul/add roundings, combined ((r0+r1)+(r2+r3))+((r4+r5)+(r6+r7)).
__global__ __launch_bounds__(256) void sq_kernel(const float* __restrict__ pts,
                                                 float* __restrict__ sqw) {
    int p = blockIdx.x * 256 + threadIdx.x;
    const float* r = pts + (size_t)p * NC;
    float acc[8];
#pragma unroll
    for (int j = 0; j < 8; ++j) acc[j] = __fmul_rn(r[j], r[j]);
#pragma unroll
    for (int i = 8; i < 64; i += 8)
#pragma unroll
        for (int j = 0; j < 8; ++j)
            acc[j] = __fadd_rn(acc[j], __fmul_rn(r[i + j], r[i + j]));
    float s01 = __fadd_rn(acc[0], acc[1]);
    float s23 = __fadd_rn(acc[2], acc[3]);
    float s45 = __fadd_rn(acc[4], acc[5]);
    float s67 = __fadd_rn(acc[6], acc[7]);
    sqw[p] = __fadd_rn(__fadd_rn(s01, s23), __fadd_rn(s45, s67));
}

// Maintain an ascending sorted 64-list, one u32 per lane:
// (fp32 key bits truncated to 20 | 12-bit idx). Key >= 0 so uint order == key
// order; truncation err 2.4e-4 rel vs rank-32->48 gap ~2.9 => superset safe.
// Threshold = lane 47 (48th smallest). Wave-parallel shift insert.
// Uniform broadcasts via readlane (SALU); only the shift uses 1 ds_permute.
__device__ __forceinline__ void stream_insert(uint32_t& list, uint32_t cand, int lane) {
    uint32_t thr = (uint32_t)__builtin_amdgcn_readlane((int)list, 47);
    u64 mask = __ballot(cand < thr);
    while (mask) {
        int src = __ffsll((long long)mask) - 1;
        uint32_t v = (uint32_t)__builtin_amdgcn_readlane((int)cand, src);  // uniform src
        int pos = __popcll(__ballot(list < v));
        uint32_t up = __shfl_up(list, 1);
        list = (lane < pos) ? list : ((lane == pos) ? v : up);
        mask &= (mask - 1);
    }
}

// Inner product as XLA:CPU dot_general (Eigen gebp) / BLAS sgemm computes it:
// per output element, ONE sequential FMA chain over k = 0..63 ascending.
__device__ __forceinline__ float ref_inner(const float4 (&xq)[16],
                                           const float4 (&yv)[16]) {
    float acc = 0.f;
#pragma unroll
    for (int i = 0; i < 16; ++i) {
        acc = __fmaf_rn(xq[i].x, yv[i].x, acc);
        acc = __fmaf_rn(xq[i].y, yv[i].y, acc);
        acc = __fmaf_rn(xq[i].z, yv[i].z, acc);
        acc = __fmaf_rn(xq[i].w, yv[i].w, acc);
    }
    return acc;
}

// Re-rank the 48 preselected candidates by the emulated reference key:
// key = fl(fl(sq_n - fl(2*inner)) + sq_m). Ties by index (top_k stable).
__device__ __forceinline__ void epilogue(uint32_t list, int n, int b, int lane,
                                         const float4 (&xq)[16],
                                         const float* __restrict__ pb,
                                         const float* __restrict__ sqb,
                                         float sqn,
                                         const float* __restrict__ xyz,
                                         float* __restrict__ out) {
    int m = (int)(list & IDXBITS);        // every lane holds a real index after chunk 0
    const float4* yr = (const float4*)(pb + (size_t)m * NC);
    float4 yv[16];
#pragma unroll
    for (int i = 0; i < 16; ++i) yv[i] = yr[i];
    float inner = ref_inner(xq, yv);
    float key = __fadd_rn(__fsub_rn(sqn, __fmul_rn(2.0f, inner)), sqb[m]);

    int rank = 0;
    uint32_t kb = __float_as_uint(key);
#pragma unroll 1
    for (int j = 0; j < TSEL; ++j) {
        float kj = __uint_as_float(
            (uint32_t)__builtin_amdgcn_readlane((int)kb, j));
        int mj = __builtin_amdgcn_readlane(m, j);
        bool less = (kj < key) || (kj == key && mj < m);   // stable: lower idx first
        rank += less ? 1 : 0;
    }
    if (lane < TSEL && rank < 2 * KOUT && (rank & 1) == 0) {  // dilation D=2: even ranks
        int k = rank >> 1;
        const float* xn = xyz + ((size_t)b * NPTS + n) * 3;
        const float* xm = xyz + ((size_t)b * NPTS + m) * 3;
        float xnx = xn[0], xny = xn[1], xnz = xn[2];
        float ox = xm[0], oy = xm[1], oz = xm[2];
        float rx = xnx - ox, ry = xny - oy, rz = xnz - oz;
        float dis = sqrtf(rx * rx + ry * ry + rz * rz);
        float* o = out + (((size_t)b * NPTS + n) * KOUT + k) * 10;
        o[0] = dis; o[1] = rx; o[2] = ry; o[3] = rz;
        o[4] = xnx; o[5] = xny; o[6] = xnz;
        o[7] = ox;  o[8] = oy;  o[9] = oz;
    }
}

__global__ __launch_bounds__(256, 2) void knn_kernel(
    const float* __restrict__ xyz,
    const float* __restrict__ pts,
    const float* __restrict__ sqw,
    float* __restrict__ out) {

    // double-buffered fp32 tile: 2 * 64 rows * 68 floats * 4B = 34.8 KB
    __shared__ __align__(16) float ylds[2][CHUNK * PADROW];

    const int tid = threadIdx.x;
    const int lane = tid & 63;
    const int wave = tid >> 6;
    const int b = blockIdx.x >> 9;                  // 512 blocks per batch
    const int rowbase = (blockIdx.x & 511) << 3;    // 8 rows per block
    const int n0 = rowbase + wave * 2;
    const int n1 = n0 + 1;
    const float* pb = pts + (size_t)b * NPTS * NC;
    const float* sqb = sqw + (size_t)b * NPTS;

    // x-features for the wave's two rows, replicated per lane (128 VGPRs)
    float4 x0q[16], x1q[16];
    {
        const float4* xr0 = (const float4*)(pb + (size_t)n0 * NC);
        const float4* xr1 = (const float4*)(pb + (size_t)n1 * NC);
#pragma unroll
        for (int i = 0; i < 16; ++i) { x0q[i] = xr0[i]; x1q[i] = xr1[i]; }
    }
    const float sqn0 = sqb[n0];
    const float sqn1 = sqb[n1];

    uint32_t list0 = 0xFFFFFFFFu, list1 = 0xFFFFFFFFu;

    const float4* gsrc = (const float4*)pb;
    float4 pf[4];
#pragma unroll
    for (int j = 0; j < 4; ++j) pf[j] = gsrc[tid + 256 * j];   // prefetch chunk 0

    // stage chunk 0 into buffer 0
#pragma unroll
    for (int j = 0; j < 4; ++j) {
        int s = tid + 256 * j;
        int ml = s >> 4;
        int c4 = s & 15;
        *(float4*)&ylds[0][ml * PADROW + c4 * 4] = pf[j];
    }
    __syncthreads();

    for (int c = 0; c < NCHUNK; ++c) {
        const int cb = c & 1;
        if (c + 1 < NCHUNK) {
#pragma unroll
            for (int j = 0; j < 4; ++j)
                pf[j] = gsrc[(size_t)(c + 1) * (CHUNK * 16) + tid + 256 * j];
        }
        {
            const int m = c * CHUNK + lane;
            const float* yr = &ylds[cb][lane * PADROW];
            float a0x = 0.f, a0y = 0.f, a0z = 0.f, a0w = 0.f;
            float a1x = 0.f, a1y = 0.f, a1z = 0.f, a1w = 0.f;
#pragma unroll
            for (int i = 0; i < 16; ++i) {
                float4 y = *(const float4*)(yr + i * 4);
                a0x = fmaf(x0q[i].x, y.x, a0x);
                a0y = fmaf(x0q[i].y, y.y, a0y);
                a0z = fmaf(x0q[i].z, y.z, a0z);
                a0w = fmaf(x0q[i].w, y.w, a0w);
                a1x = fmaf(x1q[i].x, y.x, a1x);
                a1y = fmaf(x1q[i].y, y.y, a1y);
                a1z = fmaf(x1q[i].z, y.z, a1z);
                a1w = fmaf(x1q[i].w, y.w, a1w);
            }
            float ip0 = (a0x + a0y) + (a0z + a0w);
            float ip1 = (a1x + a1y) + (a1z + a1w);
            float sqm = sqb[m];
            // streaming preselect key; ~1e-4 accurate + 2.4e-4 truncation,
            // final ranking is the epilogue's emulated key (margin ~2.9 >> 1e-3)
            float t0 = fmaxf(fmaf(-2.f, ip0, sqn0 + sqm), 0.f);
            float t1 = fmaxf(fmaf(-2.f, ip1, sqn1 + sqm), 0.f);
            uint32_t c0 = (__float_as_uint(t0) & KEYMASK) | (unsigned)m;
            uint32_t c1 = (__float_as_uint(t1) & KEYMASK) | (unsigned)m;
            stream_insert(list0, c0, lane);
            stream_insert(list1, c1, lane);
        }
        if (c + 1 < NCHUNK) {
            const int nbuf = cb ^ 1;
#pragma unroll
            for (int j = 0; j < 4; ++j) {
                int s = tid + 256 * j;
                int ml = s >> 4;
                int c4 = s & 15;
                *(float4*)&ylds[nbuf][ml * PADROW + c4 * 4] = pf[j];
            }
        }
        __syncthreads();   // one barrier per chunk: next buffer fully staged
    }

    epilogue(list0, n0, b, lane, x0q, pb, sqb, sqn0, xyz, out);
    epilogue(list1, n1, b, lane, x1q, pb, sqb, sqn1, xyz, out);
}

extern "C" void kernel_launch(void* const* d_in, const int* in_sizes, int n_in,
                              void* d_out, int out_size, void* d_ws, size_t ws_size,
                              hipStream_t stream) {
    const float* xyz = (const float*)d_in[0];   // [8,4096,3]
    const float* pts = (const float*)d_in[1];   // [8,4096,64]
    float* sqw = (float*)d_ws;                  // 32768 floats = 128 KB scratch
    float* out = (float*)d_out;                 // [8,4096,16,10]

    sq_kernel<<<(NB * NPTS) / 256, 256, 0, stream>>>(pts, sqw);
    knn_kernel<<<(NB * NPTS) / 8, 256, 0, stream>>>(xyz, pts, sqw, out);
}

// Round 7
// 1391.453 us; speedup vs baseline: 3.5872x; 1.0696x over previous
//
#include <hip/hip_runtime.h>
#include <stdint.h>

typedef unsigned long long u64;

#define NB 8
#define NPTS 4096
#define NC 64
#define KOUT 16
#define TSEL 48          // preselect size (top-48 contains true top-32; gap analysis 100x margin)
#define CHUNK 64         // candidate rows per staged chunk
#define PADROW 68        // floats per staged row: 64 + 4 pad (2-way bank aliasing = free)
#define NCHUNK (NPTS / CHUNK)
#define IDXBITS 0xFFFu   // low 12 bits hold candidate index (NPTS = 4096)
#define KEYMASK 0xFFFFF000u

// sq[p]: 8 accumulator chains over stride-8 (numpy pairwise-8 == XLA W8 reduce
// chains), separate mul/add roundings, combined ((r0+r1)+(r2+r3))+((r4+r5)+(r6+r7)).
__global__ __launch_bounds__(256) void sq_kernel(const float* __restrict__ pts,
                                                 float* __restrict__ sqw) {
    int p = blockIdx.x * 256 + threadIdx.x;
    const float* r = pts + (size_t)p * NC;
    float acc[8];
#pragma unroll
    for (int j = 0; j < 8; ++j) acc[j] = __fmul_rn(r[j], r[j]);
#pragma unroll
    for (int i = 8; i < 64; i += 8)
#pragma unroll
        for (int j = 0; j < 8; ++j)
            acc[j] = __fadd_rn(acc[j], __fmul_rn(r[i + j], r[i + j]));
    float s01 = __fadd_rn(acc[0], acc[1]);
    float s23 = __fadd_rn(acc[2], acc[3]);
    float s45 = __fadd_rn(acc[4], acc[5]);
    float s67 = __fadd_rn(acc[6], acc[7]);
    sqw[p] = __fadd_rn(__fadd_rn(s01, s23), __fadd_rn(s45, s67));
}

// Maintain an ascending sorted 64-list, one u32 per lane:
// (fp32 key bits truncated to 20 | 12-bit idx). Key >= 0 so uint order == key
// order; truncation err 2.4e-4 rel vs rank-32->48 gap ~2.9 => superset safe.
// Threshold = lane 47 (48th smallest). Wave-parallel shift insert.
// Uniform broadcasts via readlane; only the shift uses 1 ds_permute.
__device__ __forceinline__ void stream_insert(uint32_t& list, uint32_t cand, int lane) {
    uint32_t thr = (uint32_t)__builtin_amdgcn_readlane((int)list, 47);
    u64 mask = __ballot(cand < thr);
    while (mask) {
        int src = __ffsll((long long)mask) - 1;
        uint32_t v = (uint32_t)__builtin_amdgcn_readlane((int)cand, src);  // uniform src
        int pos = __popcll(__ballot(list < v));
        uint32_t up = __shfl_up(list, 1);
        list = (lane < pos) ? list : ((lane == pos) ? v : up);
        mask &= (mask - 1);
    }
}

// Re-rank the 48 preselected candidates by the emulated reference key:
// key = fl(fl(sq_n - fl(2*inner)) + sq_m), inner = ONE sequential FMA chain
// over k = 0..63 ascending (XLA:CPU dot_general / Eigen gebp order).
// Streamed x/y loads keep register pressure under the 3-wave cap.
__device__ __forceinline__ void epilogue(uint32_t list, int n, int b, int lane,
                                         const float* __restrict__ pb,
                                         const float* __restrict__ sqb,
                                         float sqn,
                                         const float* __restrict__ xyz,
                                         float* __restrict__ out) {
    int m = (int)(list & IDXBITS);        // every lane holds a real index after chunk 0
    const float4* xr = (const float4*)(pb + (size_t)n * NC);
    const float4* yr = (const float4*)(pb + (size_t)m * NC);
    float acc = 0.f;
#pragma unroll
    for (int i = 0; i < 16; ++i) {
        float4 xv = xr[i];
        float4 yv = yr[i];
        acc = __fmaf_rn(xv.x, yv.x, acc);
        acc = __fmaf_rn(xv.y, yv.y, acc);
        acc = __fmaf_rn(xv.z, yv.z, acc);
        acc = __fmaf_rn(xv.w, yv.w, acc);
    }
    float key = __fadd_rn(__fsub_rn(sqn, __fmul_rn(2.0f, acc)), sqb[m]);

    int rank = 0;
    uint32_t kb = __float_as_uint(key);
#pragma unroll 1
    for (int j = 0; j < TSEL; ++j) {
        float kj = __uint_as_float(
            (uint32_t)__builtin_amdgcn_readlane((int)kb, j));
        int mj = __builtin_amdgcn_readlane(m, j);
        bool less = (kj < key) || (kj == key && mj < m);   // stable: lower idx first
        rank += less ? 1 : 0;
    }
    if (lane < TSEL && rank < 2 * KOUT && (rank & 1) == 0) {  // dilation D=2: even ranks
        int k = rank >> 1;
        const float* xn = xyz + ((size_t)b * NPTS + n) * 3;
        const float* xm = xyz + ((size_t)b * NPTS + m) * 3;
        float xnx = xn[0], xny = xn[1], xnz = xn[2];
        float ox = xm[0], oy = xm[1], oz = xm[2];
        float rx = xnx - ox, ry = xny - oy, rz = xnz - oz;
        float dis = sqrtf(rx * rx + ry * ry + rz * rz);
        float* o = out + (((size_t)b * NPTS + n) * KOUT + k) * 10;
        o[0] = dis; o[1] = rx; o[2] = ry; o[3] = rz;
        o[4] = xnx; o[5] = xny; o[6] = xnz;
        o[7] = ox;  o[8] = oy;  o[9] = oz;
    }
}

// 3 waves/SIMD VGPR tier (cap ~85); LDS 19.6KB -> 3 blocks/CU -> 12 waves/CU.
__global__ __launch_bounds__(256, 3) void knn_kernel(
    const float* __restrict__ xyz,
    const float* __restrict__ pts,
    const float* __restrict__ sqw,
    float* __restrict__ out) {

    __shared__ __align__(16) float ylds[CHUNK * PADROW];   // 17408 B candidate tile
    __shared__ __align__(16) float xlds[8 * PADROW];       //  2176 B query tile

    const int tid = threadIdx.x;
    const int lane = tid & 63;
    const int wave = tid >> 6;
    const int b = blockIdx.x >> 9;                  // 512 blocks per batch
    const int rowbase = (blockIdx.x & 511) << 3;    // 8 rows per block
    const int n0 = rowbase + wave * 2;
    const int n1 = n0 + 1;
    const float* pb = pts + (size_t)b * NPTS * NC;
    const float* sqb = sqw + (size_t)b * NPTS;

    // stage the block's 8 query rows into LDS (read back as wave-uniform
    // ds_read_b128 broadcasts: conflict-free, frees 128 VGPRs of replicated x)
#pragma unroll
    for (int j = 0; j < 2; ++j) {
        int idx = tid + 256 * j;
        int row = idx >> 6;
        int col = idx & 63;
        xlds[row * PADROW + col] = pb[(size_t)(rowbase + row) * NC + col];
    }
    const float* xr0 = &xlds[(wave * 2 + 0) * PADROW];
    const float* xr1 = &xlds[(wave * 2 + 1) * PADROW];

    const float sqn0 = sqb[n0];
    const float sqn1 = sqb[n1];

    uint32_t list0 = 0xFFFFFFFFu, list1 = 0xFFFFFFFFu;

    const float4* gsrc = (const float4*)pb;
    float4 pf[4];
#pragma unroll
    for (int j = 0; j < 4; ++j) pf[j] = gsrc[tid + 256 * j];   // prefetch chunk 0

    for (int c = 0; c < NCHUNK; ++c) {
        __syncthreads();   // previous chunk consumed (also orders x-tile writes)
#pragma unroll
        for (int j = 0; j < 4; ++j) {
            int s = tid + 256 * j;
            int ml = s >> 4;
            int c4 = s & 15;
            *(float4*)&ylds[ml * PADROW + c4 * 4] = pf[j];
        }
        __syncthreads();
        if (c + 1 < NCHUNK) {
#pragma unroll
            for (int j = 0; j < 4; ++j)
                pf[j] = gsrc[(size_t)(c + 1) * (CHUNK * 16) + tid + 256 * j];
        }
        {
            const int m = c * CHUNK + lane;
            float sqm = sqb[m];                    // hoisted: hides under ds_reads
            const float* yr = &ylds[lane * PADROW];
            float a0x = 0.f, a0y = 0.f, a0z = 0.f, a0w = 0.f;
            float a1x = 0.f, a1y = 0.f, a1z = 0.f, a1w = 0.f;
#pragma unroll
            for (int i = 0; i < 16; ++i) {
                float4 y = *(const float4*)(yr + i * 4);
                float4 x0 = *(const float4*)(xr0 + i * 4);   // broadcast read
                float4 x1 = *(const float4*)(xr1 + i * 4);   // broadcast read
                a0x = fmaf(x0.x, y.x, a0x);
                a0y = fmaf(x0.y, y.y, a0y);
                a0z = fmaf(x0.z, y.z, a0z);
                a0w = fmaf(x0.w, y.w, a0w);
                a1x = fmaf(x1.x, y.x, a1x);
                a1y = fmaf(x1.y, y.y, a1y);
                a1z = fmaf(x1.z, y.z, a1z);
                a1w = fmaf(x1.w, y.w, a1w);
            }
            float ip0 = (a0x + a0y) + (a0z + a0w);
            float ip1 = (a1x + a1y) + (a1z + a1w);
            // streaming preselect key; ~1e-4 accurate + 2.4e-4 truncation,
            // final ranking is the epilogue's emulated key (margin ~2.9 >> 1e-3)
            float t0 = fmaxf(fmaf(-2.f, ip0, sqn0 + sqm), 0.f);
            float t1 = fmaxf(fmaf(-2.f, ip1, sqn1 + sqm), 0.f);
            uint32_t c0 = (__float_as_uint(t0) & KEYMASK) | (unsigned)m;
            uint32_t c1 = (__float_as_uint(t1) & KEYMASK) | (unsigned)m;
            stream_insert(list0, c0, lane);
            stream_insert(list1, c1, lane);
        }
    }

    epilogue(list0, n0, b, lane, pb, sqb, sqn0, xyz, out);
    epilogue(list1, n1, b, lane, pb, sqb, sqn1, xyz, out);
}

extern "C" void kernel_launch(void* const* d_in, const int* in_sizes, int n_in,
                              void* d_out, int out_size, void* d_ws, size_t ws_size,
                              hipStream_t stream) {
    const float* xyz = (const float*)d_in[0];   // [8,4096,3]
    const float* pts = (const float*)d_in[1];   // [8,4096,64]
    float* sqw = (float*)d_ws;                  // 32768 floats = 128 KB scratch
    float* out = (float*)d_out;                 // [8,4096,16,10]

    sq_kernel<<<(NB * NPTS) / 256, 256, 0, stream>>>(pts, sqw);
    knn_kernel<<<(NB * NPTS) / 8, 256, 0, stream>>>(xyz, pts, sqw, out);
}